// Round 4
// baseline (359.500 us; speedup 1.0000x reference)
//
#include <hip/hip_runtime.h>
#include <stdint.h>

// GraphSAGE on MI355X — 3 launches:
//   conv_w2t  : LDS-tiled transpose  W1t[256][512]=[w1s;w1n]^T bf16, W2t likewise
//   sage16    : merged layer 1 —  6250 blocks: nh1 = relu([h1|mean10(h2)] @ W1t^T)
//                                  625 blocks: nh0 = relu([h0|mean10(h1)] @ W1t^T)
//   sage16    : layer 2 — out = [nh0|mean10(nh1)] @ W2t^T, f32
// 16-row A-tile (16 KB LDS) built in-LDS per block; B read direct from L2.
// High occupancy (~6 blocks/CU) keeps HBM issue saturated across the
// no-HBM MFMA/L2 phase of each block.

typedef unsigned short u16;
typedef __attribute__((ext_vector_type(4))) float f32x4;
typedef __attribute__((ext_vector_type(8))) short s16x8;
typedef __attribute__((ext_vector_type(4))) unsigned short u16x4;

__device__ inline u16 f2bf(float x) {
    union { float f; uint32_t u; } v; v.f = x;
    uint32_t b = v.u;
    b += 0x7FFFu + ((b >> 16) & 1u);   // round-to-nearest-even
    return (u16)(b >> 16);
}
__device__ inline float bf2f(u16 u) {
    union { uint32_t u; float f; } v; v.u = ((uint32_t)u) << 16;
    return v.f;
}

// Transposed bf16 weight build: dst[n][koff+k] = f2bf(src[k][n]), 64x64 tiles.
// 4 source mats (w1s,w1n,w2s,w2n) x 16 tiles = 64 blocks.
__global__ __launch_bounds__(256) void conv_w2t(const float* __restrict__ w1s,
                                                const float* __restrict__ w1n,
                                                const float* __restrict__ w2s,
                                                const float* __restrict__ w2n,
                                                u16* __restrict__ W1t,
                                                u16* __restrict__ W2t) {
    __shared__ u16 t[64][66];          // +2 pad: transposed reads 2-way (free)
    const int b = blockIdx.x;
    const int mat = b >> 4;
    const int tk = ((b >> 2) & 3) * 64;    // tile k-origin within source mat
    const int tn = (b & 3) * 64;           // tile n-origin
    const float* src = (mat == 0) ? w1s : (mat == 1) ? w1n : (mat == 2) ? w2s : w2n;
    u16* dst = (mat < 2) ? W1t : W2t;
    const int koff = (mat & 1) * 256;      // self -> cols 0..255, nbr -> 256..511
    const int tid = threadIdx.x;
    const int li = tid >> 6, ln = tid & 63;
    #pragma unroll
    for (int p = 0; p < 16; ++p) {         // coalesced read over n
        int k = p * 4 + li;
        t[k][ln] = f2bf(src[(size_t)(tk + k) * 256 + tn + ln]);
    }
    __syncthreads();
    #pragma unroll
    for (int p = 0; p < 16; ++p) {         // coalesced write over k
        int n = p * 4 + li;
        dst[(size_t)(tn + n) * 512 + koff + tk + ln] = t[ln][n];
    }
}

// ---- swizzled LDS A-tile: lA[16][512] bf16, 1024 B/row, 64 16B-chunks/row
// physical chunk = logical chunk ^ (row & 7)  -> uniform-bank fragment reads
__device__ inline void store_lA(u16* lA, int r, int c, u16x4 v) {   // c mult of 4
    int byte = c * 2;
    int chunk = byte >> 4;
    int off = byte & 15;
    char* p = (char*)(lA + (size_t)r * 512) + ((chunk ^ (r & 7)) * 16) + off;
    *(u16x4*)p = v;
}
__device__ inline s16x8 read_lA(const u16* lA, int r, int k) {      // k mult of 8
    int chunk = (k * 2) >> 4;
    const char* p = (const char*)(lA + (size_t)r * 512) + ((chunk ^ (r & 7)) * 16);
    return *(const s16x8*)p;
}

// Fused SAGE layer, 16 rows x 256 cols per block.
// Blocks [0,nblk0) -> job0 (s0,n0,o0); rest -> job1.  Row counts are exact
// multiples of 16 (100000=6250*16, 10000=625*16): no tail handling anywhere.
template <bool IN_F32, bool RELU, bool OUTF32>
__global__ __launch_bounds__(256, 6) void sage16(const void* __restrict__ s0,
                                                 const void* __restrict__ n0,
                                                 void* __restrict__ o0,
                                                 const void* __restrict__ s1,
                                                 const void* __restrict__ n1,
                                                 void* __restrict__ o1,
                                                 int nblk0,
                                                 const u16* __restrict__ Bt) {
    __shared__ __align__(16) u16 lA[16 * 512];     // 16 KB
    const int b = blockIdx.x;
    const void* selfp; const void* nbrp; void* outp; int row0;
    if (b < nblk0) { selfp = s0; nbrp = n0; outp = o0; row0 = b * 16; }
    else           { selfp = s1; nbrp = n1; outp = o1; row0 = (b - nblk0) * 16; }

    const int tid = threadIdx.x;
    const int lane = tid & 63;
    const int wave = tid >> 6;

    // ---- phase 0a: self -> cols 0..255   (16 rows x 64 chunks = 1024; 4/thread)
    #pragma unroll
    for (int p = 0; p < 4; ++p) {
        int chunk = p * 256 + tid;
        int r = chunk >> 6;
        int c4 = (chunk & 63) * 4;
        int gr = row0 + r;
        u16x4 sb;
        if (IN_F32) {
            f32x4 v = *(const f32x4*)((const float*)selfp + (size_t)gr * 256 + c4);
            #pragma unroll
            for (int i = 0; i < 4; ++i) sb[i] = f2bf(v[i]);
        } else {
            sb = *(const u16x4*)((const u16*)selfp + (size_t)gr * 256 + c4);
        }
        store_lA(lA, r, c4, sb);
    }
    // ---- phase 0b: mean10(nbr) -> cols 256..511
    #pragma unroll
    for (int p = 0; p < 4; ++p) {
        int chunk = p * 256 + tid;
        int r = chunk >> 6;
        int c4 = (chunk & 63) * 4;
        int gr = row0 + r;
        f32x4 acc = {0.f, 0.f, 0.f, 0.f};
        if (IN_F32) {
            const float* nb = (const float*)nbrp + (size_t)gr * 10 * 256 + c4;
            #pragma unroll
            for (int j = 0; j < 10; ++j)
                acc += *(const f32x4*)(nb + (size_t)j * 256);
        } else {
            const u16* nb = (const u16*)nbrp + (size_t)gr * 10 * 256 + c4;
            #pragma unroll
            for (int j = 0; j < 10; ++j) {
                u16x4 v = *(const u16x4*)(nb + (size_t)j * 256);
                #pragma unroll
                for (int i = 0; i < 4; ++i) acc[i] += bf2f(v[i]);
            }
        }
        u16x4 mb;
        #pragma unroll
        for (int i = 0; i < 4; ++i) mb[i] = f2bf(acc[i] * 0.1f);
        store_lA(lA, r, 256 + c4, mb);
    }
    __syncthreads();

    // ---- phase 1: K=512 MFMA; B fragments straight from L2 (weights resident)
    f32x4 acc[4] = {};
    const int an = lane & 15;
    const int ak = (lane >> 4) * 8;
    const u16* bbase = Bt + (size_t)(wave * 64 + an) * 512 + ak;

    for (int kt = 0; kt < 8; ++kt) {
        #pragma unroll
        for (int ks = 0; ks < 2; ++ks) {
            const int kk = kt * 64 + ks * 32;
            s16x8 bF[4];
            #pragma unroll
            for (int nn = 0; nn < 4; ++nn)
                bF[nn] = *(const s16x8*)(bbase + (size_t)nn * 16 * 512 + kk);
            s16x8 aF = read_lA(lA, an, kk + ak);
            #pragma unroll
            for (int nn = 0; nn < 4; ++nn)
                acc[nn] = __builtin_amdgcn_mfma_f32_16x16x32_bf16(aF, bF[nn], acc[nn], 0, 0, 0);
        }
    }

    // ---- epilogue: C/D layout col=lane&15, row=(lane>>4)*4+j  [m89-verified]
    const int orow0 = row0 + (lane >> 4) * 4;
    const int col0 = wave * 64 + (lane & 15);
    #pragma unroll
    for (int nn = 0; nn < 4; ++nn) {
        #pragma unroll
        for (int j = 0; j < 4; ++j) {
            int r = orow0 + j;
            int cc = col0 + nn * 16;
            float v = acc[nn][j];
            if (RELU) v = fmaxf(v, 0.f);
            if (OUTF32) ((float*)outp)[(size_t)r * 256 + cc] = v;
            else        ((u16*)outp)[(size_t)r * 256 + cc] = f2bf(v);
        }
    }
}

extern "C" void kernel_launch(void* const* d_in, const int* in_sizes, int n_in,
                              void* d_out, int out_size, void* d_ws, size_t ws_size,
                              hipStream_t stream) {
    const float* h0  = (const float*)d_in[0];
    const float* h1  = (const float*)d_in[1];
    const float* h2  = (const float*)d_in[2];
    const float* w1s = (const float*)d_in[3];
    const float* w1n = (const float*)d_in[4];
    const float* w2s = (const float*)d_in[5];
    const float* w2n = (const float*)d_in[6];

    char* ws = (char*)d_ws;
    u16* W1t = (u16*)ws; ws += (size_t)256 * 512 * 2;
    u16* W2t = (u16*)ws; ws += (size_t)256 * 512 * 2;
    u16* nh1 = (u16*)ws; ws += (size_t)100000 * 256 * 2;
    u16* nh0 = (u16*)ws; ws += (size_t)10000 * 256 * 2;
    (void)ws_size; (void)in_sizes; (void)n_in; (void)out_size;

    conv_w2t<<<64, 256, 0, stream>>>(w1s, w1n, w2s, w2n, W1t, W2t);

    // merged layer 1: blocks [0,6250) -> nh1, [6250,6875) -> nh0
    sage16<true, true, false><<<6875, 256, 0, stream>>>(
        h1, h2, nh1, h0, h1, nh0, 6250, W1t);

    // layer 2: out = [nh0 | mean10(nh1)] @ W2, f32 out
    sage16<false, false, true><<<625, 256, 0, stream>>>(
        nh0, nh1, d_out, nh0, nh1, d_out, 625, W2t);
}

// Round 5
// 307.305 us; speedup vs baseline: 1.1698x; 1.1698x over previous
//
#include <hip/hip_runtime.h>
#include <stdint.h>

// GraphSAGE on MI355X — 3 launches:
//   conv_w2t  : LDS-tiled transpose  W1t[256][512]=[w1s;w1n]^T bf16, W2t likewise
//   sage_tile<32> : merged layer 1 —
//       job0 (blocks 0..312):    nh0 = relu([h0|mean10(h1)] @ W1t^T)   (dispatched first:
//                                 reads ALL of h1 -> L3-warms it for job1's self reads)
//       job1 (blocks 313..3437): nh1 = relu([h1|mean10(h2)] @ W1t^T)
//   sage_tile<16> : layer 2 — out = [nh0|mean10(nh1)] @ W2t^T, f32 (L3-resident inputs,
//                   latency-bound -> small tiles / many blocks)
// 32-row tiles for layer 1: B-panel L2 traffic is 256KB per 32 rows (the 16-row
// variant doubled it and regressed — round-3 lesson).

typedef unsigned short u16;
typedef __attribute__((ext_vector_type(4))) float f32x4;
typedef __attribute__((ext_vector_type(8))) short s16x8;
typedef __attribute__((ext_vector_type(4))) unsigned short u16x4;

__device__ inline u16 f2bf(float x) {
    union { float f; uint32_t u; } v; v.f = x;
    uint32_t b = v.u;
    b += 0x7FFFu + ((b >> 16) & 1u);   // round-to-nearest-even
    return (u16)(b >> 16);
}
__device__ inline float bf2f(u16 u) {
    union { uint32_t u; float f; } v; v.u = ((uint32_t)u) << 16;
    return v.f;
}

// Transposed bf16 weight build: dst[n][koff+k] = f2bf(src[k][n]), 64x64 tiles.
__global__ __launch_bounds__(256) void conv_w2t(const float* __restrict__ w1s,
                                                const float* __restrict__ w1n,
                                                const float* __restrict__ w2s,
                                                const float* __restrict__ w2n,
                                                u16* __restrict__ W1t,
                                                u16* __restrict__ W2t) {
    __shared__ u16 t[64][66];
    const int b = blockIdx.x;
    const int mat = b >> 4;
    const int tk = ((b >> 2) & 3) * 64;
    const int tn = (b & 3) * 64;
    const float* src = (mat == 0) ? w1s : (mat == 1) ? w1n : (mat == 2) ? w2s : w2n;
    u16* dst = (mat < 2) ? W1t : W2t;
    const int koff = (mat & 1) * 256;
    const int tid = threadIdx.x;
    const int li = tid >> 6, ln = tid & 63;
    #pragma unroll
    for (int p = 0; p < 16; ++p) {
        int k = p * 4 + li;
        t[k][ln] = f2bf(src[(size_t)(tk + k) * 256 + tn + ln]);
    }
    __syncthreads();
    #pragma unroll
    for (int p = 0; p < 16; ++p) {
        int n = p * 4 + li;
        dst[(size_t)(tn + n) * 512 + koff + tk + ln] = t[ln][n];
    }
}

// ---- swizzled LDS A-tile: lA[ROWS][512] bf16, 1024 B/row, 64 16B-chunks/row
// physical chunk = logical chunk ^ (row & 7)
__device__ inline void store_lA(u16* lA, int r, int c, u16x4 v) {   // c mult of 4
    int byte = c * 2;
    int chunk = byte >> 4;
    int off = byte & 15;
    char* p = (char*)(lA + (size_t)r * 512) + ((chunk ^ (r & 7)) * 16) + off;
    *(u16x4*)p = v;
}
__device__ inline s16x8 read_lA(const u16* lA, int r, int k) {      // k mult of 8
    int chunk = (k * 2) >> 4;
    const char* p = (const char*)(lA + (size_t)r * 512) + ((chunk ^ (r & 7)) * 16);
    return *(const s16x8*)p;
}

// Fused SAGE layer, ROWS x 256 per block. Two independent jobs split by blockIdx.
template <int ROWS, bool IN_F32, bool RELU, bool OUTF32>
__global__ __launch_bounds__(256, (ROWS == 32 ? 4 : 6))
void sage_tile(const void* __restrict__ s0, const void* __restrict__ n0,
               void* __restrict__ o0, int nrow0, int nblk0,
               const void* __restrict__ s1, const void* __restrict__ n1,
               void* __restrict__ o1, int nrow1,
               const u16* __restrict__ Bt) {
    __shared__ __align__(16) u16 lA[ROWS * 512];
    const int b = blockIdx.x;
    const void* selfp; const void* nbrp; void* outp; int row0; int nrows;
    if (b < nblk0) { selfp = s0; nbrp = n0; outp = o0; row0 = b * ROWS; nrows = nrow0; }
    else           { selfp = s1; nbrp = n1; outp = o1; row0 = (b - nblk0) * ROWS; nrows = nrow1; }

    const int tid = threadIdx.x;
    const int lane = tid & 63;
    const int wave = tid >> 6;
    constexpr int P = ROWS / 4;           // chunk-iterations per phase
    constexpr int MF = ROWS / 16;         // m-fragments per wave

    // ---- phase 0a: self -> cols 0..255
    #pragma unroll
    for (int p = 0; p < P; ++p) {
        int chunk = p * 256 + tid;
        int r = chunk >> 6;
        int c4 = (chunk & 63) * 4;
        int gr = min(row0 + r, nrows - 1);
        u16x4 sb;
        if (IN_F32) {
            f32x4 v = *(const f32x4*)((const float*)selfp + (size_t)gr * 256 + c4);
            #pragma unroll
            for (int i = 0; i < 4; ++i) sb[i] = f2bf(v[i]);
        } else {
            sb = *(const u16x4*)((const u16*)selfp + (size_t)gr * 256 + c4);
        }
        store_lA(lA, r, c4, sb);
    }
    // ---- phase 0b: mean10(nbr) -> cols 256..511
    #pragma unroll
    for (int p = 0; p < P; ++p) {
        int chunk = p * 256 + tid;
        int r = chunk >> 6;
        int c4 = (chunk & 63) * 4;
        int gr = min(row0 + r, nrows - 1);
        f32x4 acc = {0.f, 0.f, 0.f, 0.f};
        if (IN_F32) {
            const float* nb = (const float*)nbrp + (size_t)gr * 10 * 256 + c4;
            #pragma unroll
            for (int j = 0; j < 10; ++j)
                acc += *(const f32x4*)(nb + (size_t)j * 256);
        } else {
            const u16* nb = (const u16*)nbrp + (size_t)gr * 10 * 256 + c4;
            #pragma unroll
            for (int j = 0; j < 10; ++j) {
                u16x4 v = *(const u16x4*)(nb + (size_t)j * 256);
                #pragma unroll
                for (int i = 0; i < 4; ++i) acc[i] += bf2f(v[i]);
            }
        }
        u16x4 mb;
        #pragma unroll
        for (int i = 0; i < 4; ++i) mb[i] = f2bf(acc[i] * 0.1f);
        store_lA(lA, r, 256 + c4, mb);
    }
    __syncthreads();

    // ---- phase 1: K=512 MFMA; B fragments straight from L2 (weights resident)
    f32x4 acc[MF][4] = {};
    const int an = lane & 15;
    const int ak = (lane >> 4) * 8;
    const u16* bp[4];
    #pragma unroll
    for (int nn = 0; nn < 4; ++nn)
        bp[nn] = Bt + (size_t)(wave * 64 + nn * 16 + an) * 512 + ak;

    for (int kt = 0; kt < 8; ++kt) {
        const int kbase = kt * 64;
        s16x8 bF[2][4];
        #pragma unroll
        for (int ks = 0; ks < 2; ++ks)
            #pragma unroll
            for (int nn = 0; nn < 4; ++nn)
                bF[ks][nn] = *(const s16x8*)(bp[nn] + kbase + ks * 32);
        #pragma unroll
        for (int ks = 0; ks < 2; ++ks) {
            s16x8 aF[MF];
            #pragma unroll
            for (int m = 0; m < MF; ++m)
                aF[m] = read_lA(lA, m * 16 + an, kbase + ks * 32 + ak);
            #pragma unroll
            for (int m = 0; m < MF; ++m)
                #pragma unroll
                for (int nn = 0; nn < 4; ++nn)
                    acc[m][nn] = __builtin_amdgcn_mfma_f32_16x16x32_bf16(aF[m], bF[ks][nn], acc[m][nn], 0, 0, 0);
        }
    }

    // ---- epilogue: C/D layout col=lane&15, row=(lane>>4)*4+j  [m89-verified]
    const int orow0 = row0 + (lane >> 4) * 4;
    const int col0 = wave * 64 + (lane & 15);
    #pragma unroll
    for (int m = 0; m < MF; ++m) {
        #pragma unroll
        for (int nn = 0; nn < 4; ++nn) {
            #pragma unroll
            for (int j = 0; j < 4; ++j) {
                int r = orow0 + m * 16 + j;
                if (r >= nrows) continue;
                int cc = col0 + nn * 16;
                float v = acc[m][nn][j];
                if (RELU) v = fmaxf(v, 0.f);
                if (OUTF32) ((float*)outp)[(size_t)r * 256 + cc] = v;
                else        ((u16*)outp)[(size_t)r * 256 + cc] = f2bf(v);
            }
        }
    }
}

extern "C" void kernel_launch(void* const* d_in, const int* in_sizes, int n_in,
                              void* d_out, int out_size, void* d_ws, size_t ws_size,
                              hipStream_t stream) {
    const float* h0  = (const float*)d_in[0];
    const float* h1  = (const float*)d_in[1];
    const float* h2  = (const float*)d_in[2];
    const float* w1s = (const float*)d_in[3];
    const float* w1n = (const float*)d_in[4];
    const float* w2s = (const float*)d_in[5];
    const float* w2n = (const float*)d_in[6];

    char* ws = (char*)d_ws;
    u16* W1t = (u16*)ws; ws += (size_t)256 * 512 * 2;
    u16* W2t = (u16*)ws; ws += (size_t)256 * 512 * 2;
    u16* nh1 = (u16*)ws; ws += (size_t)100000 * 256 * 2;
    u16* nh0 = (u16*)ws; ws += (size_t)10016 * 256 * 2;
    (void)ws_size; (void)in_sizes; (void)n_in; (void)out_size;

    conv_w2t<<<64, 256, 0, stream>>>(w1s, w1n, w2s, w2n, W1t, W2t);

    // merged layer 1: job0 = hop-0 (313 blocks, 10000 rows, tail-clamped; reads all
    // of h1 as neighbors -> warms L3), job1 = hop-1 (3125 blocks, 100000 rows exact)
    sage_tile<32, true, true, false><<<313 + 3125, 256, 0, stream>>>(
        h0, h1, nh0, 10000, 313,
        h1, h2, nh1, 100000, W1t);

    // layer 2: out = [nh0 | mean10(nh1)] @ W2, f32 out; 16-row tiles, 625 blocks
    sage_tile<16, false, false, true><<<625, 256, 0, stream>>>(
        nh0, nh1, d_out, 10000, 625,
        nh0, nh1, d_out, 10000, W2t);
}

// Round 6
// 286.662 us; speedup vs baseline: 1.2541x; 1.0720x over previous
//
#include <hip/hip_runtime.h>
#include <stdint.h>

// GraphSAGE on MI355X — 3 launches:
//   conv_w2t  : LDS-tiled transpose  W1t[256][512]=[w1s;w1n]^T bf16, W2t likewise
//   sage_tile<64, ILV> : merged layer 1, jobs INTERLEAVED 10:1 by blockIdx —
//       group g = { 10 blocks of hop-1 (self rows 640g..640g+639) ,
//                    1 block  of hop-0 (neighbor rows 640g..640g+639) }
//       -> both readers of each h1 region are dispatch-adjacent, so the second
//          read hits L3/MALL and h1 costs HBM only once. 64-row tiles (64 KB
//          LDS, 2 blocks/CU) halve B-panel L2 traffic vs 32-row.
//   sage_tile<16> : layer 2 — out = [nh0|mean10(nh1)] @ W2t^T, f32 (L3-resident
//                   inputs, latency-bound -> small tiles / many blocks)

typedef unsigned short u16;
typedef __attribute__((ext_vector_type(4))) float f32x4;
typedef __attribute__((ext_vector_type(8))) short s16x8;
typedef __attribute__((ext_vector_type(4))) unsigned short u16x4;

__device__ inline u16 f2bf(float x) {
    union { float f; uint32_t u; } v; v.f = x;
    uint32_t b = v.u;
    b += 0x7FFFu + ((b >> 16) & 1u);   // round-to-nearest-even
    return (u16)(b >> 16);
}
__device__ inline float bf2f(u16 u) {
    union { uint32_t u; float f; } v; v.u = ((uint32_t)u) << 16;
    return v.f;
}

// Transposed bf16 weight build: dst[n][koff+k] = f2bf(src[k][n]), 64x64 tiles.
__global__ __launch_bounds__(256) void conv_w2t(const float* __restrict__ w1s,
                                                const float* __restrict__ w1n,
                                                const float* __restrict__ w2s,
                                                const float* __restrict__ w2n,
                                                u16* __restrict__ W1t,
                                                u16* __restrict__ W2t) {
    __shared__ u16 t[64][66];
    const int b = blockIdx.x;
    const int mat = b >> 4;
    const int tk = ((b >> 2) & 3) * 64;
    const int tn = (b & 3) * 64;
    const float* src = (mat == 0) ? w1s : (mat == 1) ? w1n : (mat == 2) ? w2s : w2n;
    u16* dst = (mat < 2) ? W1t : W2t;
    const int koff = (mat & 1) * 256;
    const int tid = threadIdx.x;
    const int li = tid >> 6, ln = tid & 63;
    #pragma unroll
    for (int p = 0; p < 16; ++p) {
        int k = p * 4 + li;
        t[k][ln] = f2bf(src[(size_t)(tk + k) * 256 + tn + ln]);
    }
    __syncthreads();
    #pragma unroll
    for (int p = 0; p < 16; ++p) {
        int n = p * 4 + li;
        dst[(size_t)(tn + n) * 512 + koff + tk + ln] = t[ln][n];
    }
}

// ---- swizzled LDS A-tile: lA[ROWS][512] bf16, 1024 B/row, 64 16B-chunks/row
// physical chunk = logical chunk ^ (row & 7)
__device__ inline void store_lA(u16* lA, int r, int c, u16x4 v) {   // c mult of 4
    int byte = c * 2;
    int chunk = byte >> 4;
    int off = byte & 15;
    char* p = (char*)(lA + (size_t)r * 512) + ((chunk ^ (r & 7)) * 16) + off;
    *(u16x4*)p = v;
}
__device__ inline s16x8 read_lA(const u16* lA, int r, int k) {      // k mult of 8
    int chunk = (k * 2) >> 4;
    const char* p = (const char*)(lA + (size_t)r * 512) + ((chunk ^ (r & 7)) * 16);
    return *(const s16x8*)p;
}

// Fused SAGE layer, ROWS x 256 per block. Two independent jobs.
// ILV=true : job0 interleaved as every 11th block (10 job1 : 1 job0 groups);
//            nblk0_or_fullg = number of FULL groups, tail1 = job1 tiles in the
//            final partial group (which also carries the last job0 tile).
// ILV=false: sequential split at nblk0_or_fullg (layer-2 uses a single job).
template <int ROWS, bool IN_F32, bool RELU, bool OUTF32, bool ILV>
__global__ __launch_bounds__(256, (ROWS >= 64 ? 2 : (ROWS == 32 ? 4 : 6)))
void sage_tile(const void* __restrict__ s0, const void* __restrict__ n0,
               void* __restrict__ o0, int nrow0,
               int nblk0_or_fullg, int tail1,
               const void* __restrict__ s1, const void* __restrict__ n1,
               void* __restrict__ o1, int nrow1,
               const u16* __restrict__ Bt) {
    __shared__ __align__(16) u16 lA[ROWS * 512];
    const int b = blockIdx.x;
    bool j0; int t;
    if (ILV) {
        const int fullg = nblk0_or_fullg;
        if (b < fullg * 11) {
            int g = b / 11, r = b - g * 11;
            if (r < 10) { j0 = false; t = g * 10 + r; }
            else        { j0 = true;  t = g; }
        } else {
            int i = b - fullg * 11;
            if (i < tail1) { j0 = false; t = fullg * 10 + i; }
            else           { j0 = true;  t = fullg; }
        }
    } else {
        j0 = (b < nblk0_or_fullg);
        t = j0 ? b : b - nblk0_or_fullg;
    }
    const void* selfp; const void* nbrp; void* outp; int row0; int nrows;
    if (j0) { selfp = s0; nbrp = n0; outp = o0; row0 = t * ROWS; nrows = nrow0; }
    else    { selfp = s1; nbrp = n1; outp = o1; row0 = t * ROWS; nrows = nrow1; }

    const int tid = threadIdx.x;
    const int lane = tid & 63;
    const int wave = tid >> 6;
    constexpr int P = ROWS / 4;           // chunk-iterations per phase
    constexpr int MF = ROWS / 16;         // m-fragments per wave

    // ---- phase 0a: self -> cols 0..255
    #pragma unroll
    for (int p = 0; p < P; ++p) {
        int chunk = p * 256 + tid;
        int r = chunk >> 6;
        int c4 = (chunk & 63) * 4;
        int gr = min(row0 + r, nrows - 1);
        u16x4 sb;
        if (IN_F32) {
            f32x4 v = *(const f32x4*)((const float*)selfp + (size_t)gr * 256 + c4);
            #pragma unroll
            for (int i = 0; i < 4; ++i) sb[i] = f2bf(v[i]);
        } else {
            sb = *(const u16x4*)((const u16*)selfp + (size_t)gr * 256 + c4);
        }
        store_lA(lA, r, c4, sb);
    }
    // ---- phase 0b: mean10(nbr) -> cols 256..511
    #pragma unroll
    for (int p = 0; p < P; ++p) {
        int chunk = p * 256 + tid;
        int r = chunk >> 6;
        int c4 = (chunk & 63) * 4;
        int gr = min(row0 + r, nrows - 1);
        f32x4 acc = {0.f, 0.f, 0.f, 0.f};
        if (IN_F32) {
            const float* nb = (const float*)nbrp + (size_t)gr * 10 * 256 + c4;
            #pragma unroll
            for (int j = 0; j < 10; ++j)
                acc += *(const f32x4*)(nb + (size_t)j * 256);
        } else {
            const u16* nb = (const u16*)nbrp + (size_t)gr * 10 * 256 + c4;
            #pragma unroll
            for (int j = 0; j < 10; ++j) {
                u16x4 v = *(const u16x4*)(nb + (size_t)j * 256);
                #pragma unroll
                for (int i = 0; i < 4; ++i) acc[i] += bf2f(v[i]);
            }
        }
        u16x4 mb;
        #pragma unroll
        for (int i = 0; i < 4; ++i) mb[i] = f2bf(acc[i] * 0.1f);
        store_lA(lA, r, 256 + c4, mb);
    }
    __syncthreads();

    // ---- phase 1: K=512 MFMA; B fragments straight from L2 (weights resident)
    f32x4 acc[MF][4] = {};
    const int an = lane & 15;
    const int ak = (lane >> 4) * 8;
    const u16* bp[4];
    #pragma unroll
    for (int nn = 0; nn < 4; ++nn)
        bp[nn] = Bt + (size_t)(wave * 64 + nn * 16 + an) * 512 + ak;

    for (int kt = 0; kt < 8; ++kt) {
        const int kbase = kt * 64;
        s16x8 bF[2][4];
        #pragma unroll
        for (int ks = 0; ks < 2; ++ks)
            #pragma unroll
            for (int nn = 0; nn < 4; ++nn)
                bF[ks][nn] = *(const s16x8*)(bp[nn] + kbase + ks * 32);
        #pragma unroll
        for (int ks = 0; ks < 2; ++ks) {
            s16x8 aF[MF];
            #pragma unroll
            for (int m = 0; m < MF; ++m)
                aF[m] = read_lA(lA, m * 16 + an, kbase + ks * 32 + ak);
            #pragma unroll
            for (int m = 0; m < MF; ++m)
                #pragma unroll
                for (int nn = 0; nn < 4; ++nn)
                    acc[m][nn] = __builtin_amdgcn_mfma_f32_16x16x32_bf16(aF[m], bF[ks][nn], acc[m][nn], 0, 0, 0);
        }
    }

    // ---- epilogue: C/D layout col=lane&15, row=(lane>>4)*4+j  [m89-verified]
    const int orow0 = row0 + (lane >> 4) * 4;
    const int col0 = wave * 64 + (lane & 15);
    #pragma unroll
    for (int m = 0; m < MF; ++m) {
        #pragma unroll
        for (int nn = 0; nn < 4; ++nn) {
            #pragma unroll
            for (int j = 0; j < 4; ++j) {
                int r = orow0 + m * 16 + j;
                if (r >= nrows) continue;
                int cc = col0 + nn * 16;
                float v = acc[m][nn][j];
                if (RELU) v = fmaxf(v, 0.f);
                if (OUTF32) ((float*)outp)[(size_t)r * 256 + cc] = v;
                else        ((u16*)outp)[(size_t)r * 256 + cc] = f2bf(v);
            }
        }
    }
}

extern "C" void kernel_launch(void* const* d_in, const int* in_sizes, int n_in,
                              void* d_out, int out_size, void* d_ws, size_t ws_size,
                              hipStream_t stream) {
    const float* h0  = (const float*)d_in[0];
    const float* h1  = (const float*)d_in[1];
    const float* h2  = (const float*)d_in[2];
    const float* w1s = (const float*)d_in[3];
    const float* w1n = (const float*)d_in[4];
    const float* w2s = (const float*)d_in[5];
    const float* w2n = (const float*)d_in[6];

    char* ws = (char*)d_ws;
    u16* W1t = (u16*)ws; ws += (size_t)256 * 512 * 2;
    u16* W2t = (u16*)ws; ws += (size_t)256 * 512 * 2;
    u16* nh1 = (u16*)ws; ws += (size_t)100032 * 256 * 2;
    u16* nh0 = (u16*)ws; ws += (size_t)10048 * 256 * 2;
    (void)ws_size; (void)in_sizes; (void)n_in; (void)out_size;

    conv_w2t<<<64, 256, 0, stream>>>(w1s, w1n, w2s, w2n, W1t, W2t);

    // merged layer 1, ROWS=64, interleaved 10:1.
    //   job1 (hop-1): 1563 tiles (100000 rows, last clamped)
    //   job0 (hop-0):  157 tiles (10000 rows, last clamped)
    //   full groups = 156 (11 blocks each), tail group = 3 job1 + 1 job0
    //   grid = 156*11 + 4 = 1720
    sage_tile<64, true, true, false, true><<<1720, 256, 0, stream>>>(
        h0, h1, nh0, 10000, 156, 3,
        h1, h2, nh1, 100000, W1t);

    // layer 2: out = [nh0 | mean10(nh1)] @ W2, f32 out; 16-row tiles, 625 blocks
    sage_tile<16, false, false, true, false><<<625, 256, 0, stream>>>(
        nh0, nh1, d_out, 10000, 625, 0,
        nh0, nh1, d_out, 10000, W2t);
}